// Round 2
// baseline (432.059 us; speedup 1.0000x reference)
//
#include <hip/hip_runtime.h>
#include <hip/hip_fp8.h>

// ---- problem constants ----
#define S_    2048
#define B_    16
#define H2_   1024
#define H_    512
#define N_    4096
#define T_    8192
#define L_    256
#define V_    50000
#define VPAD_ 50048   // 782 * 64

#define LOG2E_ 1.44269504088896f

typedef float  floatx4 __attribute__((ext_vector_type(4)));
typedef __bf16 bf16x8  __attribute__((ext_vector_type(8)));
typedef int    intx4   __attribute__((ext_vector_type(4)));
typedef int    intx8   __attribute__((ext_vector_type(8)));

__device__ inline unsigned short f2bf(float f) {
  unsigned u = __builtin_bit_cast(unsigned, f);
  unsigned r = u + 0x7fffu + ((u >> 16) & 1u);   // RNE
  return (unsigned short)(r >> 16);
}
__device__ inline float bf2f(unsigned short s) {
  unsigned u = ((unsigned)s) << 16;
  return __builtin_bit_cast(float, u);
}
__device__ inline unsigned char f2fp8(float f) {
  return (unsigned char)__hip_cvt_float_to_fp8(f, __HIP_SATFINITE, __HIP_E4M3);
}

// async global->LDS, 16B per lane; LDS dest = wave-uniform base + lane*16
__device__ inline void stage16(const void* g, void* l) {
  __builtin_amdgcn_global_load_lds(
      (const __attribute__((address_space(1))) void*)g,
      (__attribute__((address_space(3))) void*)l, 16, 0, 0);
}

// ---- fused prep: blocks [0,4096) gather span features -> bf16 [N_][H2_],
//      blocks [4096,8192) convert W1 (bf16), W2 (fp8 e4m3 * log2e, padded),
//      eb = exp(b2) (padded 0). Fusion overlaps latency-bound gather with
//      BW-bound convert and saves a launch. ----
__global__ __launch_bounds__(256) void prep_k(
    const float* __restrict__ hidden, const int* __restrict__ sbid,
    const int* __restrict__ sbeg, const int* __restrict__ send,
    unsigned short* __restrict__ featbf, float* __restrict__ lse,
    const float* __restrict__ W1, const float* __restrict__ W2,
    const float* __restrict__ b2, unsigned short* __restrict__ w1b,
    unsigned char* __restrict__ w2f8, float* __restrict__ ebp) {
  const int blk = (int)blockIdx.x;
  const int t = threadIdx.x;
  if (blk < N_) {
    const int n = blk;
    if (t == 0) lse[n] = 0.f;
    if (n == 0 && t == 1) lse[N_] = 0.f;                     // loss accumulator
    if (n == 0 && t == 2) ((unsigned*)lse)[N_ + 1] = 0u;     // ticket counter
    const int bid = sbid[n];
    int r = sbeg[n] - 1; if (r < 0) r += S_;     // (span_begin-1) mod S
    const int e = send[n];
    const size_t fbase = (size_t)r * (B_ * H2_) + (size_t)bid * H2_;
    const size_t bbase = (size_t)e * (B_ * H2_) + (size_t)bid * H2_;
    const int c = t * 4;                    // element index 0..1023
    const float4 v = (t < 128) ? *reinterpret_cast<const float4*>(hidden + fbase + c)
                               : *reinterpret_cast<const float4*>(hidden + bbase + c);
    unsigned short o[4];
    o[0] = f2bf(v.x); o[1] = f2bf(v.y); o[2] = f2bf(v.z); o[3] = f2bf(v.w);
    *reinterpret_cast<unsigned long long*>(featbf + (size_t)n * H2_ + c) =
        *reinterpret_cast<unsigned long long*>(o);
    return;
  }
  // ---- convert branch ----
  const int gid = (blk - N_) * 256 + t;
  const int gstride = 4096 * 256;
  for (long j = (long)gid * 8; j < (long)VPAD_ * 256; j += (long)gstride * 8) {
    int row = (int)(j >> 8);
    unsigned char o[8];
    if (row < V_) {
#pragma unroll
      for (int q = 0; q < 8; q++) o[q] = f2fp8(W2[j + q] * LOG2E_);
    } else {
#pragma unroll
      for (int q = 0; q < 8; q++) o[q] = 0;
    }
    *reinterpret_cast<unsigned long long*>(w2f8 + j) =
        *reinterpret_cast<unsigned long long*>(o);
  }
  for (int j = gid; j < L_ * H2_; j += gstride) w1b[j] = f2bf(W1[j]);
  for (int j = gid; j < VPAD_; j += gstride) ebp[j] = (j < V_) ? __expf(b2[j]) : 0.f;
}

// ---- GEMM1: x = tanh(feat @ W1^T + b1) -> xbf (bf16, loss) + xf8 (fp8, gemm2) ----
// 32x64 output tiles -> 512 blocks (2 blocks/CU; was 256 = 1/CU, latency-bound).
__global__ __launch_bounds__(256) void gemm1_k(
    const unsigned short* __restrict__ A,   // featbf [N_][H2_]
    const unsigned short* __restrict__ Bw,  // w1bf  [L_][H2_]
    const float* __restrict__ b1,
    unsigned short* __restrict__ xbf,       // [N_][L_]
    unsigned char* __restrict__ xf8) {      // [N_][L_]
  __shared__ __align__(16) unsigned short sA[32 * 64];
  __shared__ __align__(16) unsigned short sB[64 * 64];
  const int tid   = threadIdx.x;
  const int mtile = (int)(blockIdx.x >> 2) * 32;    // 128 m-tiles
  const int ntile = (int)(blockIdx.x & 3) * 64;
  const int lane = tid & 63, wave = tid >> 6;
  const int wr = (wave & 1) * 16;          // 2 m-waves x 16 rows
  const int wc = (wave >> 1) * 32;         // 2 n-waves x 32 cols
  const int fr = lane & 15, fq = lane >> 4;
  floatx4 acc[2] = {};
  for (int k0 = 0; k0 < H2_; k0 += 64) {
    {   // A tile: 32 rows x 64 cols = 256 chunks, 1 per thread
      const int r = tid >> 3, cc = tid & 7;
      const int gk = cc ^ (r & 7);
      stage16(A + (size_t)(mtile + r) * H2_ + k0 + gk * 8, &sA[tid * 8]);
    }
#pragma unroll
    for (int i = 0; i < 2; i++) {   // B tile: 64 rows x 64 cols = 512 chunks
      const int slot = tid + i * 256;
      const int r = slot >> 3, cc = slot & 7;
      const int gk = cc ^ (r & 7);
      stage16(Bw + (size_t)(ntile + r) * H2_ + k0 + gk * 8, &sB[slot * 8]);
    }
    __syncthreads();
#pragma unroll
    for (int ks = 0; ks < 2; ks++) {
      bf16x8 av, bv[2];
      {
        const int r = wr + fr, kc = ks * 4 + fq;
        av = *reinterpret_cast<const bf16x8*>(&sA[(r * 8 + (kc ^ (r & 7))) * 8]);
      }
#pragma unroll
      for (int ni = 0; ni < 2; ni++) {
        const int r = wc + ni * 16 + fr, kc = ks * 4 + fq;
        bv[ni] = *reinterpret_cast<const bf16x8*>(&sB[(r * 8 + (kc ^ (r & 7))) * 8]);
      }
#pragma unroll
      for (int ni = 0; ni < 2; ni++)
        acc[ni] = __builtin_amdgcn_mfma_f32_16x16x32_bf16(av, bv[ni], acc[ni], 0, 0, 0);
    }
    __syncthreads();
  }
#pragma unroll
  for (int ni = 0; ni < 2; ni++) {
    const int col = ntile + wc + ni * 16 + fr;
    const float bias = b1[col];
#pragma unroll
    for (int r = 0; r < 4; r++) {
      const int row = mtile + wr + fq * 4 + r;
      const float t = tanhf(acc[ni][r] + bias);
      xbf[(size_t)row * L_ + col] = f2bf(t);
      xf8[(size_t)row * L_ + col] = f2fp8(t);
    }
  }
}

// ---- GEMM2 (MX-scaled fp8, K=128, unit scales) + online sum-of-exp2 ----
// 64-row B tiles (16KB), 2 buffers = 32KB LDS; __launch_bounds__(512,6) ->
// 24 waves/CU = 3 blocks/CU = 3 independent barrier domains per SIMD, so one
// block's MFMA covers another's exp2/stage phase. 32 strips x 32 mtiles =
// 1024 blocks; 32 == 0 mod 8 keeps each strip pinned to one XCD (4 strips x
// ~400KB W2 per XCD L2). s_setprio(1) wraps the MFMA cluster (T5 regime:
// multiple barrier domains per SIMD). Epilogue: s = fma(eb, exp2(acc), s);
// w2f8 carries log2e; eb=0 kills pad rows.
__global__ __launch_bounds__(512, 6) void gemm2_k(
    const unsigned char* __restrict__ X8,   // xf8 [N_][256]
    const unsigned char* __restrict__ W8,   // fp8(W2 * log2e) [VPAD_][256]
    const float* __restrict__ ebp,          // exp(b2), pad = 0
    float* __restrict__ lse_sum) {          // [N_], pre-zeroed
  __shared__ __align__(16) unsigned char sB[2][16384];
  unsigned char* sAll = &sB[0][0];          // 32KB contiguous (A-stage view)
  const int tid   = threadIdx.x;
  const int mtile = ((int)blockIdx.x >> 5) * 128;
  const int strip = (int)blockIdx.x & 31;
  const int vt0   = (strip < 14) ? strip * 25 : 350 + (strip - 14) * 24;
  const int nt    = (strip < 14) ? 25 : 24;            // 14*25+18*24 = 782
  const int lane = tid & 63, wave = tid >> 6;
  const int wr = (wave & 3) * 32;                      // 4 m-waves x 32 rows
  const int wc = (wave >> 2) * 32;                     // 2 n-waves x 32 cols
  const int fr = lane & 15, fq = lane >> 4;

  // ---- stage A tile (128 rows x 256 = 32KB, swizzled), pull frags to regs ----
#pragma unroll
  for (int i = 0; i < 4; i++) {
    const int slot = tid + i * 512;           // 0..2047 (16B chunks)
    const int r = slot >> 4, c = slot & 15;
    stage16(X8 + (size_t)(mtile + r) * 256 + ((c ^ (r & 15)) << 4), &sAll[slot << 4]);
  }
  __syncthreads();
  intx8 af[2][2];                             // [mi][kh] : 32 B/lane each
#pragma unroll
  for (int mi = 0; mi < 2; mi++)
#pragma unroll
    for (int kh = 0; kh < 2; kh++) {
      const int r  = wr + mi * 16 + fr;
      const int c0 = kh * 8 + fq * 2;         // first 16B chunk of this frag
      *reinterpret_cast<intx4*>(&af[mi][kh]) =
          *reinterpret_cast<const intx4*>(&sAll[(r << 8) + ((c0 ^ (r & 15)) << 4)]);
      *(reinterpret_cast<intx4*>(&af[mi][kh]) + 1) =
          *reinterpret_cast<const intx4*>(&sAll[(r << 8) + (((c0 + 1) ^ (r & 15)) << 4)]);
    }
  __syncthreads();   // all waves done with A before LDS is reused for B

  float sacc[2][4];
#pragma unroll
  for (int mi = 0; mi < 2; mi++)
#pragma unroll
    for (int r = 0; r < 4; r++) sacc[mi][r] = 0.f;

  // prologue: eb + stage for tile 0 (into buf0, 64 rows = 16KB)
  float eb_cur[2], eb_nxt[2];
#pragma unroll
  for (int ni = 0; ni < 2; ni++)
    eb_nxt[ni] = ebp[vt0 * 64 + wc + ni * 16 + fr];
  {
    const unsigned char* base = W8 + ((size_t)vt0 << 14);
#pragma unroll
    for (int i = 0; i < 2; i++) {
      const int slot = tid + i * 512;         // 0..1023
      const int r = slot >> 4, c = slot & 15;
      stage16(base + ((size_t)r << 8) + ((c ^ (r & 15)) << 4), &sB[0][slot << 4]);
    }
  }

  for (int j = 0; j < nt; j++) {
#pragma unroll
    for (int ni = 0; ni < 2; ni++) eb_cur[ni] = eb_nxt[ni];
    // barrier: (a) tile j's stages drained, (b) all waves done reading
    // buf[(j+1)&1] (tile j-1) -> safe to restage it.
    __syncthreads();
    if (j + 1 < nt) {
      const int vt = vt0 + j + 1;
#pragma unroll
      for (int ni = 0; ni < 2; ni++)
        eb_nxt[ni] = ebp[vt * 64 + wc + ni * 16 + fr];
      const unsigned char* base = W8 + ((size_t)vt << 14);
      unsigned char* dst = &sB[(j + 1) & 1][0];
#pragma unroll
      for (int i = 0; i < 2; i++) {
        const int slot = tid + i * 512;
        const int r = slot >> 4, c = slot & 15;
        stage16(base + ((size_t)r << 8) + ((c ^ (r & 15)) << 4), dst + (slot << 4));
      }
    }

    const unsigned char* bb = &sB[j & 1][0];
    floatx4 acc[2][2] = {};
    __builtin_amdgcn_s_setprio(1);
#pragma unroll
    for (int kh = 0; kh < 2; kh++) {
#pragma unroll
      for (int ni = 0; ni < 2; ni++) {
        intx8 bv;
        const int r  = wc + ni * 16 + fr;
        const int c0 = kh * 8 + fq * 2;
        *reinterpret_cast<intx4*>(&bv) =
            *reinterpret_cast<const intx4*>(&bb[(r << 8) + ((c0 ^ (r & 15)) << 4)]);
        *(reinterpret_cast<intx4*>(&bv) + 1) =
            *reinterpret_cast<const intx4*>(&bb[(r << 8) + (((c0 + 1) ^ (r & 15)) << 4)]);
#pragma unroll
        for (int mi = 0; mi < 2; mi++)
          acc[mi][ni] = __builtin_amdgcn_mfma_scale_f32_16x16x128_f8f6f4(
              af[mi][kh], bv, acc[mi][ni], 0, 0,           // cbsz=0 (fp8), blgp=0 (fp8)
              0, 0x7f7f7f7f, 0, 0x7f7f7f7f);               // unit E8M0 scales
      }
    }
    __builtin_amdgcn_s_setprio(0);
    // epilogue: sacc += eb * exp2(acc)   (acc already in log2 domain)
#pragma unroll
    for (int mi = 0; mi < 2; mi++)
#pragma unroll
      for (int r = 0; r < 4; r++) {
        float s = sacc[mi][r];
#pragma unroll
        for (int ni = 0; ni < 2; ni++)
          s = fmaf(eb_cur[ni], __builtin_amdgcn_exp2f(acc[mi][ni][r]), s);
        sacc[mi][r] = s;
      }
  }

  // final reduction: sum across the 16 fr lanes, one atomic per row
#pragma unroll
  for (int mi = 0; mi < 2; mi++)
#pragma unroll
    for (int r = 0; r < 4; r++) {
      float s = sacc[mi][r];
      s += __shfl_xor(s, 1);
      s += __shfl_xor(s, 2);
      s += __shfl_xor(s, 4);
      s += __shfl_xor(s, 8);
      if (fr == 0)
        atomicAdd(&lse_sum[mtile + wr + mi * 16 + fq * 4 + r], s);
    }
}

// ---- focal loss over T tags + fused finalization (ticket) ----
__global__ __launch_bounds__(256) void loss_k(
    const unsigned short* __restrict__ xbf, const float* __restrict__ W2,
    const float* __restrict__ b2, const int* __restrict__ tsid,
    const int* __restrict__ tags, const float* __restrict__ lse_sum,
    float* __restrict__ loss_acc, unsigned* __restrict__ ticket,
    float* __restrict__ out) {
  const int lane = threadIdx.x & 63;
  const int gw = (int)(blockIdx.x * 256 + threadIdx.x) >> 6;
  const int nw = (int)(gridDim.x * 256) >> 6;
  float total = 0.f;
  for (int t = gw; t < T_; t += nw) {
    const int sid = tsid[t];
    const int v   = tags[t];
    const unsigned short* xr = xbf + (size_t)sid * L_;
    const float* w2r = W2 + (size_t)v * L_;
    const unsigned long long xv =
        *reinterpret_cast<const unsigned long long*>(xr + (lane << 2));
    const float4 wv = *reinterpret_cast<const float4*>(w2r + (lane << 2));
    float d = bf2f((unsigned short)xv) * wv.x
            + bf2f((unsigned short)(xv >> 16)) * wv.y
            + bf2f((unsigned short)(xv >> 32)) * wv.z
            + bf2f((unsigned short)(xv >> 48)) * wv.w;
#pragma unroll
    for (int m = 1; m < 64; m <<= 1) d += __shfl_xor(d, m);
    const float lp  = d + b2[v] - logf(lse_sum[sid]);
    const float pos = __expf(lp);
    total += (pos - 1.f) * lp;   // == -(1-pos)^1 * lp
  }
  if (lane == 0) atomicAdd(loss_acc, total);
  __syncthreads();
  __threadfence();
  if (threadIdx.x == 0) {
    const unsigned t = atomicAdd(ticket, 1u);
    if (t == (unsigned)gridDim.x - 1u) {
      const float v = atomicAdd(loss_acc, 0.0f);   // device-scope read
      out[0] = v / (8192.0f + 1e-5f);
    }
  }
}

// ---- host launcher ----
extern "C" void kernel_launch(void* const* d_in, const int* in_sizes, int n_in,
                              void* d_out, int out_size, void* d_ws, size_t ws_size,
                              hipStream_t stream) {
  const float* hidden = (const float*)d_in[0];
  const float* W1     = (const float*)d_in[1];
  const float* b1     = (const float*)d_in[2];
  const float* W2     = (const float*)d_in[3];
  const float* b2     = (const float*)d_in[4];
  const int* sbid = (const int*)d_in[5];
  const int* sbeg = (const int*)d_in[6];
  const int* send = (const int*)d_in[7];
  const int* tsid = (const int*)d_in[8];
  const int* tags = (const int*)d_in[9];
  float* out = (float*)d_out;

  char* ws = (char*)d_ws;
  unsigned short* featbf = (unsigned short*)(ws);              //  8,388,608 B
  unsigned short* xbf    = (unsigned short*)(ws + 8388608);    //  2,097,152 B
  unsigned short* w1bf   = (unsigned short*)(ws + 10485760);   //    524,288 B
  unsigned char*  xf8    = (unsigned char*) (ws + 11010048);   //  1,048,576 B
  unsigned char*  w2f8   = (unsigned char*) (ws + 12058624);   // 12,812,288 B
  float* ebp  = (float*)(ws + 24870912);                       //    200,192 B
  float* lse  = (float*)(ws + 25071104);                       //  N_ floats + lacc + ticket
  float* lacc = lse + N_;
  unsigned* ticket = (unsigned*)(lse + N_ + 1);

  prep_k<<<dim3(8192), dim3(256), 0, stream>>>(hidden, sbid, sbeg, send, featbf, lse,
                                               W1, W2, b2, w1bf, w2f8, ebp);
  gemm1_k<<<dim3(512), dim3(256), 0, stream>>>(featbf, w1bf, b1, xbf, xf8);
  gemm2_k<<<dim3(1024), dim3(512), 0, stream>>>(xf8, w2f8, ebp, lse);
  loss_k<<<dim3(512), dim3(256), 0, stream>>>(xbf, W2, b2, tsid, tags, lse, lacc, ticket, out);
}

// Round 3
// 330.461 us; speedup vs baseline: 1.3074x; 1.3074x over previous
//
#include <hip/hip_runtime.h>
#include <hip/hip_fp8.h>

// ---- problem constants ----
#define S_    2048
#define B_    16
#define H2_   1024
#define H_    512
#define N_    4096
#define T_    8192
#define L_    256
#define V_    50000
#define VPAD_ 50048   // 391 * 128

#define LOG2E_ 1.44269504088896f

typedef float  floatx4 __attribute__((ext_vector_type(4)));
typedef __bf16 bf16x8  __attribute__((ext_vector_type(8)));
typedef int    intx4   __attribute__((ext_vector_type(4)));
typedef int    intx8   __attribute__((ext_vector_type(8)));

__device__ inline unsigned short f2bf(float f) {
  unsigned u = __builtin_bit_cast(unsigned, f);
  unsigned r = u + 0x7fffu + ((u >> 16) & 1u);   // RNE
  return (unsigned short)(r >> 16);
}
__device__ inline float bf2f(unsigned short s) {
  unsigned u = ((unsigned)s) << 16;
  return __builtin_bit_cast(float, u);
}
__device__ inline unsigned char f2fp8(float f) {
  return (unsigned char)__hip_cvt_float_to_fp8(f, __HIP_SATFINITE, __HIP_E4M3);
}

// async global->LDS, 16B per lane; LDS dest = wave-uniform base + lane*16
__device__ inline void stage16(const void* g, void* l) {
  __builtin_amdgcn_global_load_lds(
      (const __attribute__((address_space(1))) void*)g,
      (__attribute__((address_space(3))) void*)l, 16, 0, 0);
}

// ---- fused prep: blocks [0,4096) gather span features -> bf16 [N_][H2_],
//      blocks [4096,8192) convert W1 (bf16), W2 (fp8 e4m3 * log2e, padded),
//      eb = exp(b2) (padded 0). ----
__global__ __launch_bounds__(256) void prep_k(
    const float* __restrict__ hidden, const int* __restrict__ sbid,
    const int* __restrict__ sbeg, const int* __restrict__ send,
    unsigned short* __restrict__ featbf, float* __restrict__ lse,
    const float* __restrict__ W1, const float* __restrict__ W2,
    const float* __restrict__ b2, unsigned short* __restrict__ w1b,
    unsigned char* __restrict__ w2f8, float* __restrict__ ebp) {
  const int blk = (int)blockIdx.x;
  const int t = threadIdx.x;
  if (blk < N_) {
    const int n = blk;
    if (t == 0) lse[n] = 0.f;
    if (n == 0 && t == 1) lse[N_] = 0.f;                     // loss accumulator
    if (n == 0 && t == 2) ((unsigned*)lse)[N_ + 1] = 0u;     // ticket counter
    const int bid = sbid[n];
    int r = sbeg[n] - 1; if (r < 0) r += S_;     // (span_begin-1) mod S
    const int e = send[n];
    const size_t fbase = (size_t)r * (B_ * H2_) + (size_t)bid * H2_;
    const size_t bbase = (size_t)e * (B_ * H2_) + (size_t)bid * H2_;
    const int c = t * 4;                    // element index 0..1023
    const float4 v = (t < 128) ? *reinterpret_cast<const float4*>(hidden + fbase + c)
                               : *reinterpret_cast<const float4*>(hidden + bbase + c);
    unsigned short o[4];
    o[0] = f2bf(v.x); o[1] = f2bf(v.y); o[2] = f2bf(v.z); o[3] = f2bf(v.w);
    *reinterpret_cast<unsigned long long*>(featbf + (size_t)n * H2_ + c) =
        *reinterpret_cast<unsigned long long*>(o);
    return;
  }
  // ---- convert branch ----
  const int gid = (blk - N_) * 256 + t;
  const int gstride = 4096 * 256;
  for (long j = (long)gid * 8; j < (long)VPAD_ * 256; j += (long)gstride * 8) {
    int row = (int)(j >> 8);
    unsigned char o[8];
    if (row < V_) {
#pragma unroll
      for (int q = 0; q < 8; q++) o[q] = f2fp8(W2[j + q] * LOG2E_);
    } else {
#pragma unroll
      for (int q = 0; q < 8; q++) o[q] = 0;
    }
    *reinterpret_cast<unsigned long long*>(w2f8 + j) =
        *reinterpret_cast<unsigned long long*>(o);
  }
  for (int j = gid; j < L_ * H2_; j += gstride) w1b[j] = f2bf(W1[j]);
  for (int j = gid; j < VPAD_; j += gstride) ebp[j] = (j < V_) ? __expf(b2[j]) : 0.f;
}

// ---- GEMM1: x = tanh(feat @ W1^T + b1) -> xbf (bf16, loss) + xf8 (fp8, gemm2) ----
// 32x64 output tiles -> 512 blocks (2 blocks/CU).
__global__ __launch_bounds__(256) void gemm1_k(
    const unsigned short* __restrict__ A,   // featbf [N_][H2_]
    const unsigned short* __restrict__ Bw,  // w1bf  [L_][H2_]
    const float* __restrict__ b1,
    unsigned short* __restrict__ xbf,       // [N_][L_]
    unsigned char* __restrict__ xf8) {      // [N_][L_]
  __shared__ __align__(16) unsigned short sA[32 * 64];
  __shared__ __align__(16) unsigned short sB[64 * 64];
  const int tid   = threadIdx.x;
  const int mtile = (int)(blockIdx.x >> 2) * 32;    // 128 m-tiles
  const int ntile = (int)(blockIdx.x & 3) * 64;
  const int lane = tid & 63, wave = tid >> 6;
  const int wr = (wave & 1) * 16;          // 2 m-waves x 16 rows
  const int wc = (wave >> 1) * 32;         // 2 n-waves x 32 cols
  const int fr = lane & 15, fq = lane >> 4;
  floatx4 acc[2] = {};
  for (int k0 = 0; k0 < H2_; k0 += 64) {
    {   // A tile: 32 rows x 64 cols = 256 chunks, 1 per thread
      const int r = tid >> 3, cc = tid & 7;
      const int gk = cc ^ (r & 7);
      stage16(A + (size_t)(mtile + r) * H2_ + k0 + gk * 8, &sA[tid * 8]);
    }
#pragma unroll
    for (int i = 0; i < 2; i++) {   // B tile: 64 rows x 64 cols = 512 chunks
      const int slot = tid + i * 256;
      const int r = slot >> 3, cc = slot & 7;
      const int gk = cc ^ (r & 7);
      stage16(Bw + (size_t)(ntile + r) * H2_ + k0 + gk * 8, &sB[slot * 8]);
    }
    __syncthreads();
#pragma unroll
    for (int ks = 0; ks < 2; ks++) {
      bf16x8 av, bv[2];
      {
        const int r = wr + fr, kc = ks * 4 + fq;
        av = *reinterpret_cast<const bf16x8*>(&sA[(r * 8 + (kc ^ (r & 7))) * 8]);
      }
#pragma unroll
      for (int ni = 0; ni < 2; ni++) {
        const int r = wc + ni * 16 + fr, kc = ks * 4 + fq;
        bv[ni] = *reinterpret_cast<const bf16x8*>(&sB[(r * 8 + (kc ^ (r & 7))) * 8]);
      }
#pragma unroll
      for (int ni = 0; ni < 2; ni++)
        acc[ni] = __builtin_amdgcn_mfma_f32_16x16x32_bf16(av, bv[ni], acc[ni], 0, 0, 0);
    }
    __syncthreads();
  }
#pragma unroll
  for (int ni = 0; ni < 2; ni++) {
    const int col = ntile + wc + ni * 16 + fr;
    const float bias = b1[col];
#pragma unroll
    for (int r = 0; r < 4; r++) {
      const int row = mtile + wr + fq * 4 + r;
      const float t = tanhf(acc[ni][r] + bias);
      xbf[(size_t)row * L_ + col] = f2bf(t);
      xf8[(size_t)row * L_ + col] = f2fp8(t);
    }
  }
}

// ---- GEMM2 (MX-scaled fp8, K=128, unit scales) + online sum-of-exp2 ----
// ROUND-1 known-good config (reverted from the (512,6) experiment: forcing
// 6 waves/EU capped VGPR at 40 -> accumulator spills to scratch, WRITE_SIZE
// 4->74MB, gemm2 65->170us. This structure needs ~100 VGPR; 2 blocks/CU at
// __launch_bounds__(512,4) is its occupancy ceiling).
// 512 threads (8 waves), 128-row B tiles, double-buffered 2x32KB LDS via
// global_load_lds, XOR-16B-chunk swizzle. Wave tiling 4m x 2n (af = 32 VGPR).
// mfma_scale_f32_16x16x128_f8f6f4, unit E8M0 scales. Epilogue:
// s = fma(eb, exp2(acc), s) — w2f8 carries log2e; eb=0 kills pad rows.
// 16 strips x 32 mtiles = 512 blocks; strip = blk&15 pins W2 strips to XCDs.
__global__ __launch_bounds__(512, 4) void gemm2_k(
    const unsigned char* __restrict__ X8,   // xf8 [N_][256]
    const unsigned char* __restrict__ W8,   // fp8(W2 * log2e) [VPAD_][256]
    const float* __restrict__ ebp,          // exp(b2), pad = 0
    float* __restrict__ lse_sum) {          // [N_], pre-zeroed
  __shared__ __align__(16) unsigned char sB[2][32768];
  const int tid   = threadIdx.x;
  const int mtile = ((int)blockIdx.x >> 4) * 128;
  const int strip = (int)blockIdx.x & 15;
  const int vt0   = (strip < 7) ? strip * 25 : 175 + (strip - 7) * 24;
  const int nt    = (strip < 7) ? 25 : 24;                 // 7*25+9*24 = 391
  const int lane = tid & 63, wave = tid >> 6;
  const int wr = (wave & 3) * 32;                          // 4 m-waves x 32 rows
  const int wc = (wave >> 2) * 64;                         // 2 n-waves x 64 cols
  const int fr = lane & 15, fq = lane >> 4;

  // ---- stage A tile (32KB, swizzled) into buf0, pull frags to registers ----
#pragma unroll
  for (int i = 0; i < 4; i++) {
    const int slot = tid + i * 512;           // 0..2047 (16B chunks)
    const int r = slot >> 4, c = slot & 15;
    stage16(X8 + (size_t)(mtile + r) * 256 + ((c ^ (r & 15)) << 4), &sB[0][slot << 4]);
  }
  __syncthreads();
  intx8 af[2][2];                             // [mi][kh] : 32 B/lane each
#pragma unroll
  for (int mi = 0; mi < 2; mi++)
#pragma unroll
    for (int kh = 0; kh < 2; kh++) {
      const int r  = wr + mi * 16 + fr;
      const int c0 = kh * 8 + fq * 2;         // first 16B chunk of this frag
      *reinterpret_cast<intx4*>(&af[mi][kh]) =
          *reinterpret_cast<const intx4*>(&sB[0][(r << 8) + ((c0 ^ (r & 15)) << 4)]);
      *(reinterpret_cast<intx4*>(&af[mi][kh]) + 1) =
          *reinterpret_cast<const intx4*>(&sB[0][(r << 8) + (((c0 + 1) ^ (r & 15)) << 4)]);
    }
  __syncthreads();   // all waves done with A before buf0 is reused for B

  float sacc[2][4];
#pragma unroll
  for (int mi = 0; mi < 2; mi++)
#pragma unroll
    for (int r = 0; r < 4; r++) sacc[mi][r] = 0.f;

  // prologue: eb + stage for tile 0 (into buf0)
  float eb_cur[4], eb_nxt[4];
#pragma unroll
  for (int ni = 0; ni < 4; ni++)
    eb_nxt[ni] = ebp[vt0 * 128 + wc + ni * 16 + fr];
  {
    const unsigned char* base = W8 + (size_t)vt0 * 128 * 256;
#pragma unroll
    for (int i = 0; i < 4; i++) {
      const int slot = tid + i * 512;
      const int r = slot >> 4, c = slot & 15;
      stage16(base + ((size_t)r << 8) + ((c ^ (r & 15)) << 4), &sB[0][slot << 4]);
    }
  }

  for (int j = 0; j < nt; j++) {
#pragma unroll
    for (int ni = 0; ni < 4; ni++) eb_cur[ni] = eb_nxt[ni];
    // barrier first: (a) tile j's stages drained (vmcnt0 in syncthreads),
    // (b) every wave finished reading buf[(j+1)&1] (tile j-1) -> safe restage.
    __syncthreads();
    if (j + 1 < nt) {
      const int vt = vt0 + j + 1;
#pragma unroll
      for (int ni = 0; ni < 4; ni++)
        eb_nxt[ni] = ebp[vt * 128 + wc + ni * 16 + fr];
      const unsigned char* base = W8 + (size_t)vt * 128 * 256;
      unsigned char* dst = &sB[(j + 1) & 1][0];
#pragma unroll
      for (int i = 0; i < 4; i++) {
        const int slot = tid + i * 512;
        const int r = slot >> 4, c = slot & 15;
        stage16(base + ((size_t)r << 8) + ((c ^ (r & 15)) << 4), dst + (slot << 4));
      }
    }

    const unsigned char* bb = &sB[j & 1][0];
    floatx4 acc[2][4] = {};
#pragma unroll
    for (int kh = 0; kh < 2; kh++) {
#pragma unroll
      for (int ni = 0; ni < 4; ni++) {
        intx8 bv;
        const int r  = wc + ni * 16 + fr;
        const int c0 = kh * 8 + fq * 2;
        *reinterpret_cast<intx4*>(&bv) =
            *reinterpret_cast<const intx4*>(&bb[(r << 8) + ((c0 ^ (r & 15)) << 4)]);
        *(reinterpret_cast<intx4*>(&bv) + 1) =
            *reinterpret_cast<const intx4*>(&bb[(r << 8) + (((c0 + 1) ^ (r & 15)) << 4)]);
#pragma unroll
        for (int mi = 0; mi < 2; mi++)
          acc[mi][ni] = __builtin_amdgcn_mfma_scale_f32_16x16x128_f8f6f4(
              af[mi][kh], bv, acc[mi][ni], 0, 0,           // cbsz=0 (fp8), blgp=0 (fp8)
              0, 0x7f7f7f7f, 0, 0x7f7f7f7f);               // unit E8M0 scales
      }
    }
    // epilogue: sacc += eb * exp2(acc)   (acc already in log2 domain)
#pragma unroll
    for (int mi = 0; mi < 2; mi++)
#pragma unroll
      for (int r = 0; r < 4; r++) {
        float s = sacc[mi][r];
#pragma unroll
        for (int ni = 0; ni < 4; ni++)
          s = fmaf(eb_cur[ni], __builtin_amdgcn_exp2f(acc[mi][ni][r]), s);
        sacc[mi][r] = s;
      }
  }

  // final reduction: sum across the 16 fr lanes, one atomic per row
#pragma unroll
  for (int mi = 0; mi < 2; mi++)
#pragma unroll
    for (int r = 0; r < 4; r++) {
      float s = sacc[mi][r];
      s += __shfl_xor(s, 1);
      s += __shfl_xor(s, 2);
      s += __shfl_xor(s, 4);
      s += __shfl_xor(s, 8);
      if (fr == 0)
        atomicAdd(&lse_sum[mtile + wr + mi * 16 + fq * 4 + r], s);
    }
}

// ---- focal loss over T tags + fused finalization (ticket) ----
__global__ __launch_bounds__(256) void loss_k(
    const unsigned short* __restrict__ xbf, const float* __restrict__ W2,
    const float* __restrict__ b2, const int* __restrict__ tsid,
    const int* __restrict__ tags, const float* __restrict__ lse_sum,
    float* __restrict__ loss_acc, unsigned* __restrict__ ticket,
    float* __restrict__ out) {
  const int lane = threadIdx.x & 63;
  const int gw = (int)(blockIdx.x * 256 + threadIdx.x) >> 6;
  const int nw = (int)(gridDim.x * 256) >> 6;
  float total = 0.f;
  for (int t = gw; t < T_; t += nw) {
    const int sid = tsid[t];
    const int v   = tags[t];
    const unsigned short* xr = xbf + (size_t)sid * L_;
    const float* w2r = W2 + (size_t)v * L_;
    const unsigned long long xv =
        *reinterpret_cast<const unsigned long long*>(xr + (lane << 2));
    const float4 wv = *reinterpret_cast<const float4*>(w2r + (lane << 2));
    float d = bf2f((unsigned short)xv) * wv.x
            + bf2f((unsigned short)(xv >> 16)) * wv.y
            + bf2f((unsigned short)(xv >> 32)) * wv.z
            + bf2f((unsigned short)(xv >> 48)) * wv.w;
#pragma unroll
    for (int m = 1; m < 64; m <<= 1) d += __shfl_xor(d, m);
    const float lp  = d + b2[v] - logf(lse_sum[sid]);
    const float pos = __expf(lp);
    total += (pos - 1.f) * lp;   // == -(1-pos)^1 * lp
  }
  if (lane == 0) atomicAdd(loss_acc, total);
  __syncthreads();
  __threadfence();
  if (threadIdx.x == 0) {
    const unsigned t = atomicAdd(ticket, 1u);
    if (t == (unsigned)gridDim.x - 1u) {
      const float v = atomicAdd(loss_acc, 0.0f);   // device-scope read
      out[0] = v / (8192.0f + 1e-5f);
    }
  }
}

// ---- host launcher ----
extern "C" void kernel_launch(void* const* d_in, const int* in_sizes, int n_in,
                              void* d_out, int out_size, void* d_ws, size_t ws_size,
                              hipStream_t stream) {
  const float* hidden = (const float*)d_in[0];
  const float* W1     = (const float*)d_in[1];
  const float* b1     = (const float*)d_in[2];
  const float* W2     = (const float*)d_in[3];
  const float* b2     = (const float*)d_in[4];
  const int* sbid = (const int*)d_in[5];
  const int* sbeg = (const int*)d_in[6];
  const int* send = (const int*)d_in[7];
  const int* tsid = (const int*)d_in[8];
  const int* tags = (const int*)d_in[9];
  float* out = (float*)d_out;

  char* ws = (char*)d_ws;
  unsigned short* featbf = (unsigned short*)(ws);              //  8,388,608 B
  unsigned short* xbf    = (unsigned short*)(ws + 8388608);    //  2,097,152 B
  unsigned short* w1bf   = (unsigned short*)(ws + 10485760);   //    524,288 B
  unsigned char*  xf8    = (unsigned char*) (ws + 11010048);   //  1,048,576 B
  unsigned char*  w2f8   = (unsigned char*) (ws + 12058624);   // 12,812,288 B
  float* ebp  = (float*)(ws + 24870912);                       //    200,192 B
  float* lse  = (float*)(ws + 25071104);                       //  N_ floats + lacc + ticket
  float* lacc = lse + N_;
  unsigned* ticket = (unsigned*)(lse + N_ + 1);

  prep_k<<<dim3(8192), dim3(256), 0, stream>>>(hidden, sbid, sbeg, send, featbf, lse,
                                               W1, W2, b2, w1bf, w2f8, ebp);
  gemm1_k<<<dim3(512), dim3(256), 0, stream>>>(featbf, w1bf, b1, xbf, xf8);
  gemm2_k<<<dim3(512), dim3(512), 0, stream>>>(xf8, w2f8, ebp, lse);
  loss_k<<<dim3(512), dim3(256), 0, stream>>>(xbf, W2, b2, tsid, tags, lse, lacc, ticket, out);
}

// Round 4
// 309.846 us; speedup vs baseline: 1.3944x; 1.0665x over previous
//
#include <hip/hip_runtime.h>
#include <hip/hip_fp8.h>

// ---- problem constants ----
#define S_    2048
#define B_    16
#define H2_   1024
#define H_    512
#define N_    4096
#define T_    8192
#define L_    256
#define V_    50000
#define VPAD_ 50048   // 391 * 128

#define LOG2E_ 1.44269504088896f

typedef float  floatx4 __attribute__((ext_vector_type(4)));
typedef __bf16 bf16x8  __attribute__((ext_vector_type(8)));
typedef int    intx4   __attribute__((ext_vector_type(4)));
typedef int    intx8   __attribute__((ext_vector_type(8)));

__device__ inline unsigned short f2bf(float f) {
  unsigned u = __builtin_bit_cast(unsigned, f);
  unsigned r = u + 0x7fffu + ((u >> 16) & 1u);   // RNE
  return (unsigned short)(r >> 16);
}
__device__ inline float bf2f(unsigned short s) {
  unsigned u = ((unsigned)s) << 16;
  return __builtin_bit_cast(float, u);
}
__device__ inline unsigned char f2fp8(float f) {
  return (unsigned char)__hip_cvt_float_to_fp8(f, __HIP_SATFINITE, __HIP_E4M3);
}

// async global->LDS, 16B per lane; LDS dest = wave-uniform base + lane*16
__device__ inline void stage16(const void* g, void* l) {
  __builtin_amdgcn_global_load_lds(
      (const __attribute__((address_space(1))) void*)g,
      (__attribute__((address_space(3))) void*)l, 16, 0, 0);
}

// ---- gather span features -> bf16 [N_][H2_]; also zeroes lse/loss/ticket ----
// (round-1 configuration: separate gather/convert measured 310.4 total; the
// fused-prep + retiled-gemm1 bundle measured +20us — reverted.)
__global__ __launch_bounds__(256) void gather_k(
    const float* __restrict__ hidden, const int* __restrict__ sbid,
    const int* __restrict__ sbeg, const int* __restrict__ send,
    unsigned short* __restrict__ featbf, float* __restrict__ lse) {
  const int n = blockIdx.x;
  const int t = threadIdx.x;
  if (t == 0) lse[n] = 0.f;
  if (n == 0 && t == 1) lse[N_] = 0.f;                     // loss accumulator
  if (n == 0 && t == 2) ((unsigned*)lse)[N_ + 1] = 0u;     // ticket counter
  const int bid = sbid[n];
  int r = sbeg[n] - 1; if (r < 0) r += S_;     // (span_begin-1) mod S
  const int e = send[n];
  const size_t fbase = (size_t)r * (B_ * H2_) + (size_t)bid * H2_;
  const size_t bbase = (size_t)e * (B_ * H2_) + (size_t)bid * H2_;
  const int c = t * 4;                    // element index 0..1023 (wave-uniform branch)
  const float4 v = (t < 128) ? *reinterpret_cast<const float4*>(hidden + fbase + c)
                             : *reinterpret_cast<const float4*>(hidden + bbase + c);
  unsigned short o[4];
  o[0] = f2bf(v.x); o[1] = f2bf(v.y); o[2] = f2bf(v.z); o[3] = f2bf(v.w);
  *reinterpret_cast<unsigned long long*>(featbf + (size_t)n * H2_ + c) =
      *reinterpret_cast<unsigned long long*>(o);
}

// ---- convert W1 (bf16), W2 (fp8 e4m3 * log2e, padded), eb = exp(b2) (padded 0) ----
__global__ __launch_bounds__(256) void convert_k(
    const float* __restrict__ W1, const float* __restrict__ W2,
    const float* __restrict__ b2, unsigned short* __restrict__ w1b,
    unsigned char* __restrict__ w2f8, float* __restrict__ ebp) {
  const int gid = blockIdx.x * 256 + threadIdx.x;
  const int gstride = gridDim.x * 256;
  for (long j = (long)gid * 8; j < (long)VPAD_ * 256; j += (long)gstride * 8) {
    int row = (int)(j >> 8);
    unsigned char o[8];
    if (row < V_) {
#pragma unroll
      for (int q = 0; q < 8; q++) o[q] = f2fp8(W2[j + q] * LOG2E_);
    } else {
#pragma unroll
      for (int q = 0; q < 8; q++) o[q] = 0;
    }
    *reinterpret_cast<unsigned long long*>(w2f8 + j) =
        *reinterpret_cast<unsigned long long*>(o);
  }
  for (int j = gid; j < L_ * H2_; j += gstride) w1b[j] = f2bf(W1[j]);
  for (int j = gid; j < VPAD_; j += gstride) ebp[j] = (j < V_) ? __expf(b2[j]) : 0.f;
}

// ---- GEMM1: x = tanh(feat @ W1^T + b1) -> xbf (bf16, loss) + xf8 (fp8, gemm2) ----
// round-1 config: 64x64 tiles, 256 blocks.
__global__ __launch_bounds__(256) void gemm1_k(
    const unsigned short* __restrict__ A,   // featbf [N_][H2_]
    const unsigned short* __restrict__ Bw,  // w1bf  [L_][H2_]
    const float* __restrict__ b1,
    unsigned short* __restrict__ xbf,       // [N_][L_]
    unsigned char* __restrict__ xf8) {      // [N_][L_]
  __shared__ __align__(16) unsigned short sA[64 * 64];
  __shared__ __align__(16) unsigned short sB[64 * 64];
  const int tid   = threadIdx.x;
  const int mtile = (int)(blockIdx.x >> 2) * 64;
  const int ntile = (int)(blockIdx.x & 3) * 64;
  const int lane = tid & 63, wave = tid >> 6;
  const int wr = (wave & 1) * 32, wc = (wave >> 1) * 32;
  const int fr = lane & 15, fq = lane >> 4;
  floatx4 acc[2][2] = {};
  for (int k0 = 0; k0 < H2_; k0 += 64) {
#pragma unroll
    for (int i = 0; i < 2; i++) {
      const int slot = tid + i * 256;          // 0..511 (16B chunks)
      const int r = slot >> 3, cc = slot & 7;
      const int gk = cc ^ (r & 7);             // bank swizzle on global source
      stage16(A  + (size_t)(mtile + r) * H2_ + k0 + gk * 8, &sA[slot * 8]);
      stage16(Bw + (size_t)(ntile + r) * H2_ + k0 + gk * 8, &sB[slot * 8]);
    }
    __syncthreads();
#pragma unroll
    for (int ks = 0; ks < 2; ks++) {
      bf16x8 av[2], bv[2];
#pragma unroll
      for (int mi = 0; mi < 2; mi++) {
        const int r = wr + mi * 16 + fr, kc = ks * 4 + fq;
        av[mi] = *reinterpret_cast<const bf16x8*>(&sA[(r * 8 + (kc ^ (r & 7))) * 8]);
      }
#pragma unroll
      for (int ni = 0; ni < 2; ni++) {
        const int r = wc + ni * 16 + fr, kc = ks * 4 + fq;
        bv[ni] = *reinterpret_cast<const bf16x8*>(&sB[(r * 8 + (kc ^ (r & 7))) * 8]);
      }
#pragma unroll
      for (int mi = 0; mi < 2; mi++)
#pragma unroll
        for (int ni = 0; ni < 2; ni++)
          acc[mi][ni] = __builtin_amdgcn_mfma_f32_16x16x32_bf16(av[mi], bv[ni], acc[mi][ni], 0, 0, 0);
    }
    __syncthreads();
  }
#pragma unroll
  for (int ni = 0; ni < 2; ni++) {
    const int col = ntile + wc + ni * 16 + fr;
    const float bias = b1[col];
#pragma unroll
    for (int mi = 0; mi < 2; mi++)
#pragma unroll
      for (int r = 0; r < 4; r++) {
        const int row = mtile + wr + mi * 16 + fq * 4 + r;
        const float t = tanhf(acc[mi][ni][r] + bias);
        xbf[(size_t)row * L_ + col] = f2bf(t);
        xf8[(size_t)row * L_ + col] = f2fp8(t);
      }
  }
}

// ---- GEMM2 (MX-scaled fp8, K=128, unit scales) + online sum-of-exp2 ----
// Structure identical to round-1 (known-good 310.4 total): 512 threads,
// (512,4) = 2 blocks/CU (VGPR cap 128; this kernel needs ~100 — do NOT
// raise waves/EU, round-2 proved it spills: WRITE_SIZE 4->74MB, 65->170us).
// This round's single change: intra-wave schedule. The inner loop is
// ni-pipelined — MFMAs for n-group ni are issued BEFORE the exp2/fma
// epilogue of group ni-1, so the matrix pipe stays fed during the wave's
// own VALU phase, and each MFMA cluster is wrapped in s_setprio(1)/(0)
// (T5: with 2 desync'd blocks/CU + phase split there is role diversity).
__global__ __launch_bounds__(512, 4) void gemm2_k(
    const unsigned char* __restrict__ X8,   // xf8 [N_][256]
    const unsigned char* __restrict__ W8,   // fp8(W2 * log2e) [VPAD_][256]
    const float* __restrict__ ebp,          // exp(b2), pad = 0
    float* __restrict__ lse_sum) {          // [N_], pre-zeroed
  __shared__ __align__(16) unsigned char sB[2][32768];
  const int tid   = threadIdx.x;
  const int mtile = ((int)blockIdx.x >> 4) * 128;
  const int strip = (int)blockIdx.x & 15;
  const int vt0   = (strip < 7) ? strip * 25 : 175 + (strip - 7) * 24;
  const int nt    = (strip < 7) ? 25 : 24;                 // 7*25+9*24 = 391
  const int lane = tid & 63, wave = tid >> 6;
  const int wr = (wave & 3) * 32;                          // 4 m-waves x 32 rows
  const int wc = (wave >> 2) * 64;                         // 2 n-waves x 64 cols
  const int fr = lane & 15, fq = lane >> 4;

  // ---- stage A tile (32KB, swizzled) into buf0, pull frags to registers ----
#pragma unroll
  for (int i = 0; i < 4; i++) {
    const int slot = tid + i * 512;           // 0..2047 (16B chunks)
    const int r = slot >> 4, c = slot & 15;
    stage16(X8 + (size_t)(mtile + r) * 256 + ((c ^ (r & 15)) << 4), &sB[0][slot << 4]);
  }
  __syncthreads();
  intx8 af[2][2];                             // [mi][kh] : 32 B/lane each
#pragma unroll
  for (int mi = 0; mi < 2; mi++)
#pragma unroll
    for (int kh = 0; kh < 2; kh++) {
      const int r  = wr + mi * 16 + fr;
      const int c0 = kh * 8 + fq * 2;         // first 16B chunk of this frag
      *reinterpret_cast<intx4*>(&af[mi][kh]) =
          *reinterpret_cast<const intx4*>(&sB[0][(r << 8) + ((c0 ^ (r & 15)) << 4)]);
      *(reinterpret_cast<intx4*>(&af[mi][kh]) + 1) =
          *reinterpret_cast<const intx4*>(&sB[0][(r << 8) + (((c0 + 1) ^ (r & 15)) << 4)]);
    }
  __syncthreads();   // all waves done with A before buf0 is reused for B

  float sacc[2][4];
#pragma unroll
  for (int mi = 0; mi < 2; mi++)
#pragma unroll
    for (int r = 0; r < 4; r++) sacc[mi][r] = 0.f;

  // prologue: eb + stage for tile 0 (into buf0)
  float eb_cur[4], eb_nxt[4];
#pragma unroll
  for (int ni = 0; ni < 4; ni++)
    eb_nxt[ni] = ebp[vt0 * 128 + wc + ni * 16 + fr];
  {
    const unsigned char* base = W8 + (size_t)vt0 * 128 * 256;
#pragma unroll
    for (int i = 0; i < 4; i++) {
      const int slot = tid + i * 512;
      const int r = slot >> 4, c = slot & 15;
      stage16(base + ((size_t)r << 8) + ((c ^ (r & 15)) << 4), &sB[0][slot << 4]);
    }
  }

  for (int j = 0; j < nt; j++) {
#pragma unroll
    for (int ni = 0; ni < 4; ni++) eb_cur[ni] = eb_nxt[ni];
    // barrier first: (a) tile j's stages drained (vmcnt0 in syncthreads),
    // (b) every wave finished reading buf[(j+1)&1] (tile j-1) -> safe restage.
    __syncthreads();
    if (j + 1 < nt) {
      const int vt = vt0 + j + 1;
#pragma unroll
      for (int ni = 0; ni < 4; ni++)
        eb_nxt[ni] = ebp[vt * 128 + wc + ni * 16 + fr];
      const unsigned char* base = W8 + (size_t)vt * 128 * 256;
      unsigned char* dst = &sB[(j + 1) & 1][0];
#pragma unroll
      for (int i = 0; i < 4; i++) {
        const int slot = tid + i * 512;
        const int r = slot >> 4, c = slot & 15;
        stage16(base + ((size_t)r << 8) + ((c ^ (r & 15)) << 4), dst + (slot << 4));
      }
    }

    const unsigned char* bb = &sB[j & 1][0];
    floatx4 acc[2][4] = {};
    // ni-pipelined compute: issue MFMAs for group ni, then run the exp2
    // epilogue of group ni-1 while they land.
#pragma unroll
    for (int ni = 0; ni < 4; ni++) {
      __builtin_amdgcn_s_setprio(1);
#pragma unroll
      for (int kh = 0; kh < 2; kh++) {
        intx8 bv;
        const int r  = wc + ni * 16 + fr;
        const int c0 = kh * 8 + fq * 2;
        *reinterpret_cast<intx4*>(&bv) =
            *reinterpret_cast<const intx4*>(&bb[(r << 8) + ((c0 ^ (r & 15)) << 4)]);
        *(reinterpret_cast<intx4*>(&bv) + 1) =
            *reinterpret_cast<const intx4*>(&bb[(r << 8) + (((c0 + 1) ^ (r & 15)) << 4)]);
#pragma unroll
        for (int mi = 0; mi < 2; mi++)
          acc[mi][ni] = __builtin_amdgcn_mfma_scale_f32_16x16x128_f8f6f4(
              af[mi][kh], bv, acc[mi][ni], 0, 0,           // cbsz=0 (fp8), blgp=0 (fp8)
              0, 0x7f7f7f7f, 0, 0x7f7f7f7f);               // unit E8M0 scales
      }
      __builtin_amdgcn_s_setprio(0);
      if (ni > 0) {
        const int pi = ni - 1;
#pragma unroll
        for (int mi = 0; mi < 2; mi++)
#pragma unroll
          for (int r = 0; r < 4; r++)
            sacc[mi][r] = fmaf(eb_cur[pi], __builtin_amdgcn_exp2f(acc[mi][pi][r]),
                               sacc[mi][r]);
      }
    }
    // tail epilogue: ni = 3
#pragma unroll
    for (int mi = 0; mi < 2; mi++)
#pragma unroll
      for (int r = 0; r < 4; r++)
        sacc[mi][r] = fmaf(eb_cur[3], __builtin_amdgcn_exp2f(acc[mi][3][r]),
                           sacc[mi][r]);
  }

  // final reduction: sum across the 16 fr lanes, one atomic per row
#pragma unroll
  for (int mi = 0; mi < 2; mi++)
#pragma unroll
    for (int r = 0; r < 4; r++) {
      float s = sacc[mi][r];
      s += __shfl_xor(s, 1);
      s += __shfl_xor(s, 2);
      s += __shfl_xor(s, 4);
      s += __shfl_xor(s, 8);
      if (fr == 0)
        atomicAdd(&lse_sum[mtile + wr + mi * 16 + fq * 4 + r], s);
    }
}

// ---- focal loss over T tags + fused finalization (ticket) ----
__global__ __launch_bounds__(256) void loss_k(
    const unsigned short* __restrict__ xbf, const float* __restrict__ W2,
    const float* __restrict__ b2, const int* __restrict__ tsid,
    const int* __restrict__ tags, const float* __restrict__ lse_sum,
    float* __restrict__ loss_acc, unsigned* __restrict__ ticket,
    float* __restrict__ out) {
  const int lane = threadIdx.x & 63;
  const int gw = (int)(blockIdx.x * 256 + threadIdx.x) >> 6;
  const int nw = (int)(gridDim.x * 256) >> 6;
  float total = 0.f;
  for (int t = gw; t < T_; t += nw) {
    const int sid = tsid[t];
    const int v   = tags[t];
    const unsigned short* xr = xbf + (size_t)sid * L_;
    const float* w2r = W2 + (size_t)v * L_;
    float d = 0.f;
#pragma unroll
    for (int q = 0; q < 4; q++) {
      const int j = lane * 4 + q;
      d += bf2f(xr[j]) * w2r[j];
    }
#pragma unroll
    for (int m = 1; m < 64; m <<= 1) d += __shfl_xor(d, m);
    const float lp  = d + b2[v] - logf(lse_sum[sid]);
    const float pos = __expf(lp);
    total += (pos - 1.f) * lp;   // == -(1-pos)^1 * lp
  }
  if (lane == 0) atomicAdd(loss_acc, total);
  __syncthreads();
  __threadfence();
  if (threadIdx.x == 0) {
    const unsigned t = atomicAdd(ticket, 1u);
    if (t == (unsigned)gridDim.x - 1u) {
      const float v = atomicAdd(loss_acc, 0.0f);   // device-scope read
      out[0] = v / (8192.0f + 1e-5f);
    }
  }
}

// ---- host launcher ----
extern "C" void kernel_launch(void* const* d_in, const int* in_sizes, int n_in,
                              void* d_out, int out_size, void* d_ws, size_t ws_size,
                              hipStream_t stream) {
  const float* hidden = (const float*)d_in[0];
  const float* W1     = (const float*)d_in[1];
  const float* b1     = (const float*)d_in[2];
  const float* W2     = (const float*)d_in[3];
  const float* b2     = (const float*)d_in[4];
  const int* sbid = (const int*)d_in[5];
  const int* sbeg = (const int*)d_in[6];
  const int* send = (const int*)d_in[7];
  const int* tsid = (const int*)d_in[8];
  const int* tags = (const int*)d_in[9];
  float* out = (float*)d_out;

  char* ws = (char*)d_ws;
  unsigned short* featbf = (unsigned short*)(ws);              //  8,388,608 B
  unsigned short* xbf    = (unsigned short*)(ws + 8388608);    //  2,097,152 B
  unsigned short* w1bf   = (unsigned short*)(ws + 10485760);   //    524,288 B
  unsigned char*  xf8    = (unsigned char*) (ws + 11010048);   //  1,048,576 B
  unsigned char*  w2f8   = (unsigned char*) (ws + 12058624);   // 12,812,288 B
  float* ebp  = (float*)(ws + 24870912);                       //    200,192 B
  float* lse  = (float*)(ws + 25071104);                       //  N_ floats + lacc + ticket
  float* lacc = lse + N_;
  unsigned* ticket = (unsigned*)(lse + N_ + 1);

  gather_k<<<dim3(N_), dim3(256), 0, stream>>>(hidden, sbid, sbeg, send, featbf, lse);
  convert_k<<<dim3(4096), dim3(256), 0, stream>>>(W1, W2, b2, w1bf, w2f8, ebp);
  gemm1_k<<<dim3(256), dim3(256), 0, stream>>>(featbf, w1bf, b1, xbf, xf8);
  gemm2_k<<<dim3(512), dim3(512), 0, stream>>>(xf8, w2f8, ebp, lse);
  loss_k<<<dim3(256), dim3(256), 0, stream>>>(xbf, W2, b2, tsid, tags, lse, lacc, ticket, out);
}